// Round 1
// baseline (921.583 us; speedup 1.0000x reference)
//
#include <hip/hip_runtime.h>
#include <math.h>

// Problem constants (unit_gcn): N=64, C=64, T=300, V=25, S=3
#define NN 64
#define CC 64
#define TDIM 300
#define VV 25
#define SS 3

// ws float layout:
//   [0, 1875)     : normalized adjacency A[s][v][w]
//   [1920, 2048)  : stats (sum[64], sumsq[64])
//   [2048, 2176)  : scale[64], shift[64]

// ---------------------------------------------------------------------------
// K1: normalize adjacency columns (L2 over v per (s,w)), zero the stats accums
// ---------------------------------------------------------------------------
__global__ void k_prep(const float* __restrict__ PA, float* __restrict__ ws) {
    int tid = threadIdx.x;  // 128 threads
    if (tid < 128) ws[1920 + tid] = 0.0f;
    if (tid < SS * VV) {
        int s = tid / VV, w = tid - s * VV;
        float ss = 0.0f;
        for (int v = 0; v < VV; ++v) {
            float p = PA[(s * VV + v) * VV + w];
            ss += p * p;
        }
        float inv = 1.0f / (sqrtf(ss) + 1e-4f);
        for (int v = 0; v < VV; ++v)
            ws[s * 625 + v * 25 + w] = PA[(s * VV + v) * VV + w] * inv;
    }
}

// ---------------------------------------------------------------------------
// K2: per (n, t-tile) block computes Y_nt = sum_s W_s * (X_nt * A_s)  (no bias:
// a per-channel constant bias cancels exactly through training-mode BN).
// Writes pre-BN y into d_out, accumulates per-channel sum / sumsq into stats.
// Thread map: w = tid&31 (active w<25), grp = tid>>5 -> 8 channels each.
// LDS: A (7.5K) + W_s[c][o] pad68 (17.4K) + X[c][v] pad28 (7K) + P[c][w] (6.4K)
// ---------------------------------------------------------------------------
__global__ __launch_bounds__(256) void k_main(const float* __restrict__ x,
                                              const float* __restrict__ W,
                                              const float* __restrict__ wsA,
                                              float* __restrict__ ypre,
                                              float* __restrict__ stats) {
    __shared__ __align__(16) float A_lds[3 * 625];
    __shared__ __align__(16) float W_lds[64 * 68];
    __shared__ __align__(16) float X_lds[64 * 28];
    __shared__ __align__(16) float P_lds[64 * 25];

    const int tid = threadIdx.x;
    const int n = blockIdx.y;
    const int t0 = blockIdx.x * 10;
    const int w = tid & 31;
    const int grp = tid >> 5;
    const bool act = (w < VV);

    for (int i = tid; i < 3 * 625; i += 256) A_lds[i] = wsA[i];

    float ssum[8], ssq[8];
#pragma unroll
    for (int i = 0; i < 8; ++i) { ssum[i] = 0.0f; ssq[i] = 0.0f; }

    for (int t = t0; t < t0 + 10; ++t) {
        // stage X: x[n, c, t, 0:25] -> X_lds[c][v], rows padded to 28 (zero fill)
        for (int i = tid; i < 64 * 28; i += 256) {
            int c = i / 28;
            int v = i - c * 28;
            X_lds[i] = (v < VV) ? x[n * 480000 + c * 7500 + t * 25 + v] : 0.0f;
        }

        float yacc[8];
#pragma unroll
        for (int i = 0; i < 8; ++i) yacc[i] = 0.0f;

        for (int s = 0; s < 3; ++s) {
            __syncthreads();  // prev stage-Y done with W_lds/P_lds; X/A ready
            // stage W: W[s][o][c] -> W_lds[c*68 + o] (coalesced global read)
            for (int i = tid; i < 4096; i += 256) {
                int o = i >> 6, c = i & 63;
                W_lds[c * 68 + o] = W[s * 4096 + i];
            }
            // stage P: P[c][w] = sum_v X[c][v] * A_s[v][w]
            if (act) {
                float av[25];
#pragma unroll
                for (int v = 0; v < 25; ++v) av[v] = A_lds[s * 625 + v * 25 + w];
#pragma unroll
                for (int i = 0; i < 8; ++i) {
                    int c = grp * 8 + i;
                    float acc = 0.0f;
#pragma unroll
                    for (int v = 0; v < 25; ++v)
                        acc = fmaf(X_lds[c * 28 + v], av[v], acc);
                    P_lds[c * 25 + w] = acc;
                }
            }
            __syncthreads();
            // stage Y: yacc[o] += sum_c W_s[o][c] * P[c][w]
            if (act) {
#pragma unroll 8
                for (int c = 0; c < 64; ++c) {
                    float pv = P_lds[c * 25 + w];
#pragma unroll
                    for (int i = 0; i < 8; ++i)
                        yacc[i] = fmaf(W_lds[c * 68 + grp * 8 + i], pv, yacc[i]);
                }
            }
        }

        if (act) {
            int base = n * 480000 + t * 25 + w;
#pragma unroll
            for (int i = 0; i < 8; ++i) {
                int o = grp * 8 + i;
                float y = yacc[i];
                ypre[base + o * 7500] = y;
                ssum[i] += y;
                ssq[i] = fmaf(y, y, ssq[i]);
            }
        }
    }

    // reduce across the 32 w-lanes sharing each grp (inactive lanes hold 0)
#pragma unroll
    for (int i = 0; i < 8; ++i) {
        float a = ssum[i], b = ssq[i];
        for (int m = 16; m > 0; m >>= 1) {
            a += __shfl_xor(a, m, 32);
            b += __shfl_xor(b, m, 32);
        }
        if (w == 0) {
            atomicAdd(&stats[grp * 8 + i], a);
            atomicAdd(&stats[64 + grp * 8 + i], b);
        }
    }
}

// ---------------------------------------------------------------------------
// K3: finalize BN scale/shift per channel
// ---------------------------------------------------------------------------
__global__ void k_stats(const float* __restrict__ stats,
                        const float* __restrict__ gamma,
                        const float* __restrict__ beta,
                        float* __restrict__ scsh) {
    int o = threadIdx.x;
    if (o >= 64) return;
    const float invn = 1.0f / 480000.0f;  // N*T*V
    float mean = stats[o] * invn;
    float var = stats[64 + o] * invn - mean * mean;
    float inv = rsqrtf(var + 1e-5f);
    float sc = gamma[o] * inv;
    scsh[o] = sc;
    scsh[64 + o] = beta[o] - mean * sc;
}

// ---------------------------------------------------------------------------
// K4: out = relu(scale[o]*ypre + shift[o] + x), in place on d_out, float4
// ---------------------------------------------------------------------------
__global__ __launch_bounds__(256) void k_bnrelu(const float* __restrict__ x,
                                                const float* __restrict__ scsh,
                                                float* out) {
    int i = blockIdx.x * 256 + threadIdx.x;  // 7,680,000 float4 elements
    if (i >= 7680000) return;
    int plane = i / 1875;  // (n*64 + o); 7500 floats = 1875 float4 per plane
    int o = plane & 63;
    float sc = scsh[o], sh = scsh[64 + o];
    float4 y = ((const float4*)out)[i];
    float4 xx = ((const float4*)x)[i];
    float4 r;
    r.x = fmaxf(fmaf(y.x, sc, sh) + xx.x, 0.0f);
    r.y = fmaxf(fmaf(y.y, sc, sh) + xx.y, 0.0f);
    r.z = fmaxf(fmaf(y.z, sc, sh) + xx.z, 0.0f);
    r.w = fmaxf(fmaf(y.w, sc, sh) + xx.w, 0.0f);
    ((float4*)out)[i] = r;
}

// ---------------------------------------------------------------------------
extern "C" void kernel_launch(void* const* d_in, const int* in_sizes, int n_in,
                              void* d_out, int out_size, void* d_ws, size_t ws_size,
                              hipStream_t stream) {
    const float* x = (const float*)d_in[0];
    const float* PA = (const float*)d_in[1];
    const float* W = (const float*)d_in[2];
    // d_in[3] = b : per-channel constant bias cancels exactly through
    // training-mode BatchNorm (mean subtraction) -> unused.
    const float* gamma = (const float*)d_in[4];
    const float* beta = (const float*)d_in[5];
    float* wsf = (float*)d_ws;
    float* out = (float*)d_out;

    k_prep<<<1, 128, 0, stream>>>(PA, wsf);
    dim3 g2(30, 64);  // (t-tiles of 10, n)
    k_main<<<g2, 256, 0, stream>>>(x, W, wsf, out, wsf + 1920);
    k_stats<<<1, 64, 0, stream>>>(wsf + 1920, gamma, beta, wsf + 2048);
    k_bnrelu<<<30000, 256, 0, stream>>>(x, wsf + 2048, out);
}

// Round 2
// 448.227 us; speedup vs baseline: 2.0561x; 2.0561x over previous
//
#include <hip/hip_runtime.h>
#include <math.h>

// Problem constants (unit_gcn): N=64, C=64, T=300, V=25, S=3
// ws float layout:
//   [0, 1875)     : normalized adjacency A[s][v][w]
//   [1920, 2048)  : stats (sum[64], sumsq[64])
//   [2048, 2176)  : scale[64], shift[64]

typedef __attribute__((ext_vector_type(8))) short bf16x8;
typedef __attribute__((ext_vector_type(4))) float f32x4;

__device__ inline ushort f2bf(float f) {
    union { float f; unsigned u; } v; v.f = f;
    unsigned r = v.u + 0x7fffu + ((v.u >> 16) & 1u);
    return (ushort)(r >> 16);
}

// ---------------------------------------------------------------------------
// K1: normalize adjacency columns (L2 over v per (s,w)), zero the stats accums
// ---------------------------------------------------------------------------
__global__ void k_prep(const float* __restrict__ PA, float* __restrict__ ws) {
    int tid = threadIdx.x;  // 128 threads
    if (tid < 128) ws[1920 + tid] = 0.0f;
    if (tid < 75) {
        int s = tid / 25, w = tid - s * 25;
        float ss = 0.0f;
        for (int v = 0; v < 25; ++v) {
            float p = PA[(s * 25 + v) * 25 + w];
            ss += p * p;
        }
        float inv = 1.0f / (sqrtf(ss) + 1e-4f);
        for (int v = 0; v < 25; ++v)
            ws[s * 625 + v * 25 + w] = PA[(s * 25 + v) * 25 + w] * inv;
    }
}

// ---------------------------------------------------------------------------
// K2 (MFMA): per block: one n, Tt=5 time steps (60 t-tiles, exact).
//  GEMM1: Z_s[o,(t,v)] = sum_c W_s[o,c] * X[c,(t,v)]   M=64 N=128(pad) K=64
//  GEMM2: y[(t,o),w]  += sum_v Z_s * A_s[v,w]          K=25->32, N=25->2 tiles
// Bias b.sum(0) cancels exactly through training-mode BN -> dropped.
// LDS: X bf16 [tv 128][c stride 72] (rows 144B, 16B-aligned, 2-way free)
//      Z bf16 [(t*64+o) 320][v stride 40] (rows 80B, 16B-aligned, 2-way free)
// Each wave owns o-strip [wv*16, wv*16+16): writes+reads only its own Z rows,
// so no barrier inside the s-loop.
// ---------------------------------------------------------------------------
__global__ __launch_bounds__(256) void k_main(const float* __restrict__ x,
                                              const float* __restrict__ W,
                                              const float* __restrict__ An,
                                              float* __restrict__ ypre,
                                              float* __restrict__ stats) {
    __shared__ __align__(16) ushort Xl[128 * 72];
    __shared__ __align__(16) ushort Zl[320 * 40];
    __shared__ float sst[128];

    const int tid = threadIdx.x;
    const int wv = tid >> 6;
    const int lane = tid & 63;
    const int col = lane & 15;
    const int quad = lane >> 4;
    const int strip = wv << 4;
    const int n = blockIdx.y;
    const int t0 = blockIdx.x * 5;

    // stage X: x[n, c, t0*25 + tv] -> Xl[tv*72 + c]; tv>=125 zero-padded
    {
        const float* xp = x + n * 480000 + t0 * 25;
        for (int i = tid; i < 8192; i += 256) {
            int c = i >> 7, tv = i & 127;
            float g = (tv < 125) ? xp[c * 7500 + tv] : 0.0f;
            Xl[tv * 72 + c] = f2bf(g);
        }
    }
    // zero Z pad cols v=24..31 (v>=25 must not be NaN garbage; 24 is rewritten)
    for (int i = tid; i < 320 * 8; i += 256) {
        int r = i >> 3, v = 24 + (i & 7);
        Zl[r * 40 + v] = 0;
    }
    __syncthreads();

    f32x4 yacc[5][2];
#pragma unroll
    for (int t = 0; t < 5; ++t)
#pragma unroll
        for (int j = 0; j < 2; ++j) yacc[t][j] = (f32x4){0.f, 0.f, 0.f, 0.f};

    for (int s = 0; s < 3; ++s) {
        // W A-frags: o = strip+col, c = kt*32 + quad*8 + j  (L2-hot, 48KB total)
        bf16x8 wf[2];
        {
            const float* wp = W + s * 4096 + (strip + col) * 64 + quad * 8;
#pragma unroll
            for (int kt = 0; kt < 2; ++kt) {
                bf16x8 f;
#pragma unroll
                for (int j = 0; j < 8; ++j) f[j] = (short)f2bf(wp[kt * 32 + j]);
                wf[kt] = f;
            }
        }
        // adjacency B-frags: k=v=quad*8+j, n=w=nt2*16+col; OOB -> 0
        bf16x8 af[2];
#pragma unroll
        for (int nt2 = 0; nt2 < 2; ++nt2) {
            int w = nt2 * 16 + col;
            bf16x8 f;
#pragma unroll
            for (int j = 0; j < 8; ++j) {
                int v = quad * 8 + j;
                float a = (v < 25 && w < 25) ? An[s * 625 + v * 25 + w] : 0.0f;
                f[j] = (short)f2bf(a);
            }
            af[nt2] = f;
        }
        // GEMM1: wave's o-strip of Z
#pragma unroll
        for (int nt = 0; nt < 8; ++nt) {
            f32x4 z = (f32x4){0.f, 0.f, 0.f, 0.f};
            const int rb = (nt * 16 + col) * 72 + quad * 8;
            bf16x8 x0 = *(const bf16x8*)&Xl[rb];
            bf16x8 x1 = *(const bf16x8*)&Xl[rb + 32];
            z = __builtin_amdgcn_mfma_f32_16x16x32_bf16(wf[0], x0, z, 0, 0, 0);
            z = __builtin_amdgcn_mfma_f32_16x16x32_bf16(wf[1], x1, z, 0, 0, 0);
            int colg = nt * 16 + col;
            if (colg < 125) {
                int t = (colg * 41) >> 10;  // /25, exact for colg<128
                int v = colg - t * 25;
                int row = (t << 6) + strip + (quad << 2);
#pragma unroll
                for (int r = 0; r < 4; ++r) Zl[(row + r) * 40 + v] = f2bf(z[r]);
            }
        }
        // GEMM2: consume own Z rows (intra-wave LDS dependency only)
#pragma unroll
        for (int t = 0; t < 5; ++t) {
            bf16x8 zf = *(const bf16x8*)&Zl[(((t << 6) + strip + col) * 40) + quad * 8];
            yacc[t][0] = __builtin_amdgcn_mfma_f32_16x16x32_bf16(zf, af[0], yacc[t][0], 0, 0, 0);
            yacc[t][1] = __builtin_amdgcn_mfma_f32_16x16x32_bf16(zf, af[1], yacc[t][1], 0, 0, 0);
        }
    }

    // epilogue: write pre-BN y, accumulate per-channel stats
    // D layout: col(lane&15)=w(+16*nt2), row(quad*4+r) -> o = strip+quad*4+r
    float ssum[4] = {0.f, 0.f, 0.f, 0.f}, ssq[4] = {0.f, 0.f, 0.f, 0.f};
    const int obase = strip + (quad << 2);
#pragma unroll
    for (int t = 0; t < 5; ++t) {
#pragma unroll
        for (int nt2 = 0; nt2 < 2; ++nt2) {
            int w = nt2 * 16 + col;
            if (w < 25) {
                float* yp = ypre + n * 480000 + obase * 7500 + (t0 + t) * 25 + w;
                f32x4 f = yacc[t][nt2];
#pragma unroll
                for (int r = 0; r < 4; ++r) {
                    float yv = f[r];
                    yp[r * 7500] = yv;
                    ssum[r] += yv;
                    ssq[r] = fmaf(yv, yv, ssq[r]);
                }
            }
        }
    }
#pragma unroll
    for (int r = 0; r < 4; ++r) {
        float a = ssum[r], b = ssq[r];
        for (int m = 1; m < 16; m <<= 1) {
            a += __shfl_xor(a, m, 64);
            b += __shfl_xor(b, m, 64);
        }
        if (col == 0) {  // unique (wv,quad,r) -> unique o: plain stores
            sst[obase + r] = a;
            sst[64 + obase + r] = b;
        }
    }
    __syncthreads();
    if (tid < 128) atomicAdd(&stats[tid], sst[tid]);
}

// ---------------------------------------------------------------------------
// K3: finalize BN scale/shift per channel
// ---------------------------------------------------------------------------
__global__ void k_stats(const float* __restrict__ stats,
                        const float* __restrict__ gamma,
                        const float* __restrict__ beta,
                        float* __restrict__ scsh) {
    int o = threadIdx.x;
    if (o >= 64) return;
    const float invn = 1.0f / 480000.0f;  // N*T*V
    float mean = stats[o] * invn;
    float var = stats[64 + o] * invn - mean * mean;
    float inv = rsqrtf(var + 1e-5f);
    float sc = gamma[o] * inv;
    scsh[o] = sc;
    scsh[64 + o] = beta[o] - mean * sc;
}

// ---------------------------------------------------------------------------
// K4: out = relu(scale[o]*ypre + shift[o] + x), in place on d_out, float4
// ---------------------------------------------------------------------------
__global__ __launch_bounds__(256) void k_bnrelu(const float* __restrict__ x,
                                                const float* __restrict__ scsh,
                                                float* out) {
    int i = blockIdx.x * 256 + threadIdx.x;  // 7,680,000 float4 elements
    if (i >= 7680000) return;
    int plane = i / 1875;  // (n*64 + o); 7500 floats = 1875 float4 per plane
    int o = plane & 63;
    float sc = scsh[o], sh = scsh[64 + o];
    float4 y = ((const float4*)out)[i];
    float4 xx = ((const float4*)x)[i];
    float4 r;
    r.x = fmaxf(fmaf(y.x, sc, sh) + xx.x, 0.0f);
    r.y = fmaxf(fmaf(y.y, sc, sh) + xx.y, 0.0f);
    r.z = fmaxf(fmaf(y.z, sc, sh) + xx.z, 0.0f);
    r.w = fmaxf(fmaf(y.w, sc, sh) + xx.w, 0.0f);
    ((float4*)out)[i] = r;
}

// ---------------------------------------------------------------------------
extern "C" void kernel_launch(void* const* d_in, const int* in_sizes, int n_in,
                              void* d_out, int out_size, void* d_ws, size_t ws_size,
                              hipStream_t stream) {
    const float* x = (const float*)d_in[0];
    const float* PA = (const float*)d_in[1];
    const float* W = (const float*)d_in[2];
    // d_in[3] = b : cancels through training-mode BN -> unused
    const float* gamma = (const float*)d_in[4];
    const float* beta = (const float*)d_in[5];
    float* wsf = (float*)d_ws;
    float* out = (float*)d_out;

    k_prep<<<1, 128, 0, stream>>>(PA, wsf);
    dim3 g2(60, 64);  // (t-tiles of 5, n)
    k_main<<<g2, 256, 0, stream>>>(x, W, wsf, out, wsf + 1920);
    k_stats<<<1, 64, 0, stream>>>(wsf + 1920, gamma, beta, wsf + 2048);
    k_bnrelu<<<30000, 256, 0, stream>>>(x, wsf + 2048, out);
}

// Round 3
// 413.342 us; speedup vs baseline: 2.2296x; 1.0844x over previous
//
#include <hip/hip_runtime.h>
#include <math.h>

// Problem constants (unit_gcn): N=64, C=64, T=300, V=25, S=3
// ws float layout:
//   [0, 1875)        : normalized adjacency A[s][v][w]      (fallback path)
//   [1920, 2048)     : stats (sum[64], sumsq[64])
//   [2048, 2176)     : scale[64], shift[64]
//   [2176, 8320)     : W-frag table, ushort[12288]: frag f=((s*2+kt)*4+wv)*64+lane
//   [8320, 9856)     : A-frag table, ushort[3072]:  frag f=((s*2+nt2))*64+lane
#define WS_FAST_BYTES 40960

typedef __attribute__((ext_vector_type(8))) short bf16x8;
typedef __attribute__((ext_vector_type(4))) float f32x4;

__device__ inline ushort f2bf(float f) {
    union { float f; unsigned u; } v; v.f = f;
    unsigned r = v.u + 0x7fffu + ((v.u >> 16) & 1u);
    return (ushort)(r >> 16);
}

// ---------------------------------------------------------------------------
// K1: normalize adjacency (L2 over v per (s,w)), zero stats, build MFMA
// fragment tables (once for the whole grid — 3840x redundancy removed).
// ---------------------------------------------------------------------------
__global__ __launch_bounds__(256) void k_prep(const float* __restrict__ PA,
                                              const float* __restrict__ W,
                                              float* __restrict__ ws, int full) {
    __shared__ float Al[1875];
    const int tid = threadIdx.x;
    for (int i = tid; i < 1875; i += 256) Al[i] = PA[i];
    if (tid < 128) ws[1920 + tid] = 0.0f;
    __syncthreads();
    if (tid < 75) {
        int s = tid / 25, w = tid - s * 25;
        float ss = 0.0f;
        for (int v = 0; v < 25; ++v) {
            float p = Al[s * 625 + v * 25 + w];
            ss += p * p;
        }
        float inv = 1.0f / (sqrtf(ss) + 1e-4f);
        for (int v = 0; v < 25; ++v) {
            float a = Al[s * 625 + v * 25 + w] * inv;
            Al[s * 625 + v * 25 + w] = a;
            ws[s * 625 + v * 25 + w] = a;
        }
    }
    __syncthreads();
    if (!full) return;
    // W-frag table: element j of frag f: W[s][o=wv*16+col][c=kt*32+quad*8+j]
    ushort* wt = (ushort*)(ws + 2176);
    for (int f = tid; f < 1536; f += 256) {
        int lane = f & 63, rest = f >> 6;
        int wv = rest & 3, sk = rest >> 2;
        int kt = sk & 1, s = sk >> 1;
        int col = lane & 15, quad = lane >> 4;
        const float* wp = W + s * 4096 + (wv * 16 + col) * 64 + kt * 32 + quad * 8;
#pragma unroll
        for (int j = 0; j < 8; ++j) wt[f * 8 + j] = f2bf(wp[j]);
    }
    // A-frag table: element j: A[s][v=quad*8+j][w=nt2*16+col], OOB->0
    ushort* at = (ushort*)(ws + 8320);
    for (int f = tid; f < 384; f += 256) {
        int lane = f & 63, rest = f >> 6;
        int nt2 = rest & 1, s = rest >> 1;
        int col = lane & 15, quad = lane >> 4;
        int w = nt2 * 16 + col;
#pragma unroll
        for (int j = 0; j < 8; ++j) {
            int v = quad * 8 + j;
            float a = (v < 25 && w < 25) ? Al[s * 625 + v * 25 + w] : 0.0f;
            at[f * 8 + j] = f2bf(a);
        }
    }
}

// ---------------------------------------------------------------------------
// K2 fast (MFMA): grid (12, 64) = 768 blocks = exactly 3/CU, one round.
// Per block: one n, 25 t-steps as 5 subtiles of 5.
//  GEMM1: Z_s[o,(t,v)] = sum_c W_s[o,c] * X[c,(t,v)]   M=64 N=128(pad) K=64
//  GEMM2: y[(t,o),w]  += sum_v Z_s * A_s[v,w]          K=25->32, N=25->2 tiles
// All W/A fragments hoisted from precomputed tables (12 dwordx4 per lane,
// zero global traffic in the s-loop). Bias cancels through BN -> dropped.
// Each wave owns o-strip [wv*16,wv*16+16): no barrier inside the s-loop.
// ---------------------------------------------------------------------------
__global__ __launch_bounds__(256, 3) void k_main_v3(const float* __restrict__ x,
                                                    const float* __restrict__ ws,
                                                    float* __restrict__ ypre,
                                                    float* __restrict__ stats) {
    __shared__ __align__(16) ushort Xl[128 * 72];
    __shared__ __align__(16) ushort Zl[320 * 40];
    __shared__ float sst[128];

    const int tid = threadIdx.x;
    const int wv = tid >> 6;
    const int lane = tid & 63;
    const int col = lane & 15;
    const int quad = lane >> 4;
    const int strip = wv << 4;
    const int n = blockIdx.y;
    const int tb = blockIdx.x * 25;

    // hoist all fragments (L2-hot 30KB tables)
    const ushort* wt = (const ushort*)(ws + 2176);
    const ushort* at = (const ushort*)(ws + 8320);
    bf16x8 wf[3][2], af[3][2];
#pragma unroll
    for (int s = 0; s < 3; ++s) {
#pragma unroll
        for (int kt = 0; kt < 2; ++kt)
            wf[s][kt] = *(const bf16x8*)&wt[(((s * 2 + kt) * 4 + wv) * 64 + lane) * 8];
#pragma unroll
        for (int nt2 = 0; nt2 < 2; ++nt2)
            af[s][nt2] = *(const bf16x8*)&at[((s * 2 + nt2) * 64 + lane) * 8];
    }
    // zero Z pad cols v=25..31 once (GEMM1 rewrites v<25 every subtile)
    for (int i = tid; i < 320 * 8; i += 256)
        Zl[(i >> 3) * 40 + 24 + (i & 7)] = 0;

    float ssum[4] = {0.f, 0.f, 0.f, 0.f}, ssq[4] = {0.f, 0.f, 0.f, 0.f};
    const int obase = strip + (quad << 2);

    for (int sub = 0; sub < 5; ++sub) {
        const int t0 = tb + sub * 5;
        __syncthreads();  // all waves done reading Xl of previous subtile
        // stage X: x[n, c, t0*25 + tv] -> Xl[tv*72 + c]; tv>=125 zero
        const float* xp = x + n * 480000 + t0 * 25;
#pragma unroll 8
        for (int i = tid; i < 8192; i += 256) {
            int c = i >> 7, tv = i & 127;
            float g = (tv < 125) ? xp[c * 7500 + tv] : 0.0f;
            Xl[tv * 72 + c] = f2bf(g);
        }
        __syncthreads();

        f32x4 yacc[5][2];
#pragma unroll
        for (int t = 0; t < 5; ++t)
#pragma unroll
            for (int j = 0; j < 2; ++j) yacc[t][j] = (f32x4){0.f, 0.f, 0.f, 0.f};

#pragma unroll
        for (int s = 0; s < 3; ++s) {
            // GEMM1: wave's o-strip of Z
#pragma unroll
            for (int nt = 0; nt < 8; ++nt) {
                f32x4 z = (f32x4){0.f, 0.f, 0.f, 0.f};
                const int rb = (nt * 16 + col) * 72 + quad * 8;
                bf16x8 x0 = *(const bf16x8*)&Xl[rb];
                bf16x8 x1 = *(const bf16x8*)&Xl[rb + 32];
                z = __builtin_amdgcn_mfma_f32_16x16x32_bf16(wf[s][0], x0, z, 0, 0, 0);
                z = __builtin_amdgcn_mfma_f32_16x16x32_bf16(wf[s][1], x1, z, 0, 0, 0);
                int colg = nt * 16 + col;
                if (colg < 125) {
                    int t = (colg * 41) >> 10;  // /25, exact for colg<128
                    int v = colg - t * 25;
                    int row = (t << 6) + strip + (quad << 2);
#pragma unroll
                    for (int r = 0; r < 4; ++r) Zl[(row + r) * 40 + v] = f2bf(z[r]);
                }
            }
            // GEMM2: consume own Z rows (intra-wave LDS dependency only)
#pragma unroll
            for (int t = 0; t < 5; ++t) {
                bf16x8 zf = *(const bf16x8*)&Zl[((t << 6) + strip + col) * 40 + quad * 8];
                yacc[t][0] = __builtin_amdgcn_mfma_f32_16x16x32_bf16(zf, af[s][0], yacc[t][0], 0, 0, 0);
                yacc[t][1] = __builtin_amdgcn_mfma_f32_16x16x32_bf16(zf, af[s][1], yacc[t][1], 0, 0, 0);
            }
        }

        // epilogue: D layout col(lane&15)=w(+16*nt2), row(quad*4+r)=o-offset
#pragma unroll
        for (int t = 0; t < 5; ++t) {
#pragma unroll
            for (int nt2 = 0; nt2 < 2; ++nt2) {
                int w = nt2 * 16 + col;
                if (w < 25) {
                    float* yp = ypre + n * 480000 + obase * 7500 + (t0 + t) * 25 + w;
                    f32x4 f = yacc[t][nt2];
#pragma unroll
                    for (int r = 0; r < 4; ++r) {
                        float yv = f[r];
                        yp[r * 7500] = yv;
                        ssum[r] += yv;
                        ssq[r] = fmaf(yv, yv, ssq[r]);
                    }
                }
            }
        }
    }

    // per-channel stats: reduce over the 16 w-lanes (o is lane-uniform per r)
#pragma unroll
    for (int r = 0; r < 4; ++r) {
        float a = ssum[r], b = ssq[r];
        for (int m = 1; m < 16; m <<= 1) {
            a += __shfl_xor(a, m, 64);
            b += __shfl_xor(b, m, 64);
        }
        if (col == 0) {  // unique (wv,quad,r) -> unique o
            sst[obase + r] = a;
            sst[64 + obase + r] = b;
        }
    }
    __syncthreads();
    if (tid < 128) atomicAdd(&stats[tid], sst[tid]);
}

// ---------------------------------------------------------------------------
// K2 fallback (R2-proven path, needs only ~9KB ws): grid (60, 64)
// ---------------------------------------------------------------------------
__global__ __launch_bounds__(256) void k_main_fb(const float* __restrict__ x,
                                                 const float* __restrict__ W,
                                                 const float* __restrict__ An,
                                                 float* __restrict__ ypre,
                                                 float* __restrict__ stats) {
    __shared__ __align__(16) ushort Xl[128 * 72];
    __shared__ __align__(16) ushort Zl[320 * 40];
    __shared__ float sst[128];

    const int tid = threadIdx.x;
    const int wv = tid >> 6;
    const int lane = tid & 63;
    const int col = lane & 15;
    const int quad = lane >> 4;
    const int strip = wv << 4;
    const int n = blockIdx.y;
    const int t0 = blockIdx.x * 5;

    {
        const float* xp = x + n * 480000 + t0 * 25;
        for (int i = tid; i < 8192; i += 256) {
            int c = i >> 7, tv = i & 127;
            float g = (tv < 125) ? xp[c * 7500 + tv] : 0.0f;
            Xl[tv * 72 + c] = f2bf(g);
        }
    }
    for (int i = tid; i < 320 * 8; i += 256)
        Zl[(i >> 3) * 40 + 24 + (i & 7)] = 0;
    __syncthreads();

    f32x4 yacc[5][2];
#pragma unroll
    for (int t = 0; t < 5; ++t)
#pragma unroll
        for (int j = 0; j < 2; ++j) yacc[t][j] = (f32x4){0.f, 0.f, 0.f, 0.f};

    for (int s = 0; s < 3; ++s) {
        bf16x8 wf[2];
        {
            const float* wp = W + s * 4096 + (strip + col) * 64 + quad * 8;
#pragma unroll
            for (int kt = 0; kt < 2; ++kt) {
                bf16x8 f;
#pragma unroll
                for (int j = 0; j < 8; ++j) f[j] = (short)f2bf(wp[kt * 32 + j]);
                wf[kt] = f;
            }
        }
        bf16x8 af[2];
#pragma unroll
        for (int nt2 = 0; nt2 < 2; ++nt2) {
            int w = nt2 * 16 + col;
            bf16x8 f;
#pragma unroll
            for (int j = 0; j < 8; ++j) {
                int v = quad * 8 + j;
                float a = (v < 25 && w < 25) ? An[s * 625 + v * 25 + w] : 0.0f;
                f[j] = (short)f2bf(a);
            }
            af[nt2] = f;
        }
#pragma unroll
        for (int nt = 0; nt < 8; ++nt) {
            f32x4 z = (f32x4){0.f, 0.f, 0.f, 0.f};
            const int rb = (nt * 16 + col) * 72 + quad * 8;
            bf16x8 x0 = *(const bf16x8*)&Xl[rb];
            bf16x8 x1 = *(const bf16x8*)&Xl[rb + 32];
            z = __builtin_amdgcn_mfma_f32_16x16x32_bf16(wf[0], x0, z, 0, 0, 0);
            z = __builtin_amdgcn_mfma_f32_16x16x32_bf16(wf[1], x1, z, 0, 0, 0);
            int colg = nt * 16 + col;
            if (colg < 125) {
                int t = (colg * 41) >> 10;
                int v = colg - t * 25;
                int row = (t << 6) + strip + (quad << 2);
#pragma unroll
                for (int r = 0; r < 4; ++r) Zl[(row + r) * 40 + v] = f2bf(z[r]);
            }
        }
#pragma unroll
        for (int t = 0; t < 5; ++t) {
            bf16x8 zf = *(const bf16x8*)&Zl[((t << 6) + strip + col) * 40 + quad * 8];
            yacc[t][0] = __builtin_amdgcn_mfma_f32_16x16x32_bf16(zf, af[0], yacc[t][0], 0, 0, 0);
            yacc[t][1] = __builtin_amdgcn_mfma_f32_16x16x32_bf16(zf, af[1], yacc[t][1], 0, 0, 0);
        }
    }

    float ssum[4] = {0.f, 0.f, 0.f, 0.f}, ssq[4] = {0.f, 0.f, 0.f, 0.f};
    const int obase = strip + (quad << 2);
#pragma unroll
    for (int t = 0; t < 5; ++t) {
#pragma unroll
        for (int nt2 = 0; nt2 < 2; ++nt2) {
            int w = nt2 * 16 + col;
            if (w < 25) {
                float* yp = ypre + n * 480000 + obase * 7500 + (t0 + t) * 25 + w;
                f32x4 f = yacc[t][nt2];
#pragma unroll
                for (int r = 0; r < 4; ++r) {
                    float yv = f[r];
                    yp[r * 7500] = yv;
                    ssum[r] += yv;
                    ssq[r] = fmaf(yv, yv, ssq[r]);
                }
            }
        }
    }
#pragma unroll
    for (int r = 0; r < 4; ++r) {
        float a = ssum[r], b = ssq[r];
        for (int m = 1; m < 16; m <<= 1) {
            a += __shfl_xor(a, m, 64);
            b += __shfl_xor(b, m, 64);
        }
        if (col == 0) {
            sst[obase + r] = a;
            sst[64 + obase + r] = b;
        }
    }
    __syncthreads();
    if (tid < 128) atomicAdd(&stats[tid], sst[tid]);
}

// ---------------------------------------------------------------------------
// K3: finalize BN scale/shift per channel
// ---------------------------------------------------------------------------
__global__ void k_stats(const float* __restrict__ stats,
                        const float* __restrict__ gamma,
                        const float* __restrict__ beta,
                        float* __restrict__ scsh) {
    int o = threadIdx.x;
    if (o >= 64) return;
    const float invn = 1.0f / 480000.0f;  // N*T*V
    float mean = stats[o] * invn;
    float var = stats[64 + o] * invn - mean * mean;
    float inv = rsqrtf(var + 1e-5f);
    float sc = gamma[o] * inv;
    scsh[o] = sc;
    scsh[64 + o] = beta[o] - mean * sc;
}

// ---------------------------------------------------------------------------
// K4: out = relu(scale[o]*ypre + shift[o] + x), in place on d_out, float4
// ---------------------------------------------------------------------------
__global__ __launch_bounds__(256) void k_bnrelu(const float* __restrict__ x,
                                                const float* __restrict__ scsh,
                                                float* out) {
    int i = blockIdx.x * 256 + threadIdx.x;  // 7,680,000 float4 elements
    if (i >= 7680000) return;
    int plane = i / 1875;  // (n*64 + o); 1875 float4 per (n,o) plane
    int o = plane & 63;
    float sc = scsh[o], sh = scsh[64 + o];
    float4 y = ((const float4*)out)[i];
    float4 xx = ((const float4*)x)[i];
    float4 r;
    r.x = fmaxf(fmaf(y.x, sc, sh) + xx.x, 0.0f);
    r.y = fmaxf(fmaf(y.y, sc, sh) + xx.y, 0.0f);
    r.z = fmaxf(fmaf(y.z, sc, sh) + xx.z, 0.0f);
    r.w = fmaxf(fmaf(y.w, sc, sh) + xx.w, 0.0f);
    ((float4*)out)[i] = r;
}

// ---------------------------------------------------------------------------
extern "C" void kernel_launch(void* const* d_in, const int* in_sizes, int n_in,
                              void* d_out, int out_size, void* d_ws, size_t ws_size,
                              hipStream_t stream) {
    const float* x = (const float*)d_in[0];
    const float* PA = (const float*)d_in[1];
    const float* W = (const float*)d_in[2];
    // d_in[3] = b : cancels through training-mode BN -> unused
    const float* gamma = (const float*)d_in[4];
    const float* beta = (const float*)d_in[5];
    float* wsf = (float*)d_ws;
    float* out = (float*)d_out;

    const int fast = (ws_size >= WS_FAST_BYTES) ? 1 : 0;
    k_prep<<<1, 256, 0, stream>>>(PA, W, wsf, fast);
    if (fast) {
        dim3 g2(12, 64);  // 25 t-steps per block, 768 blocks = 3/CU, one round
        k_main_v3<<<g2, 256, 0, stream>>>(x, wsf, out, wsf + 1920);
    } else {
        dim3 g2(60, 64);
        k_main_fb<<<g2, 256, 0, stream>>>(x, W, wsf, out, wsf + 1920);
    }
    k_stats<<<1, 64, 0, stream>>>(wsf + 1920, gamma, beta, wsf + 2048);
    k_bnrelu<<<30000, 256, 0, stream>>>(x, wsf + 2048, out);
}